// Round 4
// baseline (374.463 us; speedup 1.0000x reference)
//
#include <hip/hip_runtime.h>

// GLIF single timestep, N=8192.
// I = sigmoid(w @ g + x_in); v' = v + (v_rest - v + I)/tau_m;
// thresh = theta_s + theta_v; spiked_soft = sigmoid(v' - thresh);
// v_new = (v' >= thresh) ? v_rest : v'.
// Outputs: d_out[0:N] = v_new, d_out[N:2N] = spiked_soft.
// Cost = streaming 268 MB of w once -> HBM-bound, floor ~41-43 us.
//
// Round 4 (A/B vs round 3, single variable): drop the non-temporal flag on
// the w loads. Rationale: the harness restores w on-device immediately
// before every timed launch, so much of w may be L3-resident; NT loads
// forgo those hits. Also hoists lane-0 scalar param loads above the dot
// loop (latency hiding, sub-us).

#define NN 8192
#define THREADS 512
#define ROWS_PER_BLOCK (THREADS / 64)   // 8 rows, one wave each

typedef float floatx4 __attribute__((ext_vector_type(4)));

__global__ __launch_bounds__(THREADS) void glif_kernel(
    const float* __restrict__ x_in,
    const float* __restrict__ w,
    const float* __restrict__ v_in,
    const float* __restrict__ g,
    const float* __restrict__ v_rest,
    const float* __restrict__ tau_m,
    const float* __restrict__ theta_s,
    const float* __restrict__ theta_v,
    float* __restrict__ out_v,
    float* __restrict__ out_spike)
{
    __shared__ float sg[NN];  // 32 KiB: whole g vector staged once per block

    const int tid = threadIdx.x;

    // Cooperative coalesced stage of g into LDS (16 B/lane).
    const floatx4* g4 = reinterpret_cast<const floatx4*>(g);
    floatx4* sg4 = reinterpret_cast<floatx4*>(sg);
    for (int i = tid; i < NN / 4; i += THREADS) {
        sg4[i] = g4[i];
    }

    const int wave = tid >> 6;
    const int lane = tid & 63;
    const int row  = blockIdx.x * ROWS_PER_BLOCK + wave;

    // Lane 0 issues its scalar parameter loads early; results consumed
    // after the dot loop, so their latency hides under the streaming.
    float xi = 0.f, vv = 0.f, vr = 0.f, tm = 1.f, ts = 0.f, tv = 0.f;
    if (lane == 0) {
        xi = x_in[row];
        vv = v_in[row];
        vr = v_rest[row];
        tm = tau_m[row];
        ts = theta_s[row];
        tv = theta_v[row];
    }

    __syncthreads();

    // One wave per row: dot(w[row,:], g). 2048 float4 per row / 64 lanes
    // = 32 x 16B loads/lane, coalesced (1 KiB per wave instruction),
    // independent -> deep memory pipeline. Plain loads: let w hit L3
    // (restored on-device just before launch).
    const floatx4* wrow4 = reinterpret_cast<const floatx4*>(w + (size_t)row * NN);
    float ax = 0.f, ay = 0.f, az = 0.f, aw = 0.f;
    #pragma unroll 8
    for (int j = lane; j < NN / 4; j += 64) {
        floatx4 a = wrow4[j];
        floatx4 b = sg4[j];
        ax = __builtin_fmaf(a.x, b.x, ax);
        ay = __builtin_fmaf(a.y, b.y, ay);
        az = __builtin_fmaf(a.z, b.z, az);
        aw = __builtin_fmaf(a.w, b.w, aw);
    }
    float acc = (ax + ay) + (az + aw);

    // 64-lane butterfly reduce.
    #pragma unroll
    for (int off = 32; off > 0; off >>= 1)
        acc += __shfl_down(acc, off, 64);

    if (lane == 0) {
        // Elementwise GLIF tail for this row (scalar, negligible cost).
        float I  = 1.0f / (1.0f + expf(-(acc + xi)));
        float v  = vv + (vr - vv + I) / tm;
        float thresh = ts + tv;
        float ss = 1.0f / (1.0f + expf(-(v - thresh)));
        float vn = (v >= thresh) ? vr : v;
        out_v[row]     = vn;
        out_spike[row] = ss;
    }
}

extern "C" void kernel_launch(void* const* d_in, const int* in_sizes, int n_in,
                              void* d_out, int out_size, void* d_ws, size_t ws_size,
                              hipStream_t stream) {
    // setup_inputs() order:
    // 0:x_in 1:w 2:v 3:g 4:v_rest 5:tau_m 6:tau_g 7:theta_s 8:theta_v 9:b_s 10:a_v 11:b_v
    const float* x_in    = (const float*)d_in[0];
    const float* w       = (const float*)d_in[1];
    const float* v       = (const float*)d_in[2];
    const float* g       = (const float*)d_in[3];
    const float* v_rest  = (const float*)d_in[4];
    const float* tau_m   = (const float*)d_in[5];
    const float* theta_s = (const float*)d_in[7];
    const float* theta_v = (const float*)d_in[8];

    float* out_v     = (float*)d_out;        // [N] v_new
    float* out_spike = (float*)d_out + NN;   // [N] spiked_soft

    const int blocks = NN / ROWS_PER_BLOCK;  // 1024
    glif_kernel<<<blocks, THREADS, 0, stream>>>(
        x_in, w, v, g, v_rest, tau_m, theta_s, theta_v, out_v, out_spike);
}

// Round 5
// 351.789 us; speedup vs baseline: 1.0645x; 1.0645x over previous
//
#include <hip/hip_runtime.h>

// GLIF single timestep, N=8192.
// I = sigmoid(w @ g + x_in); v' = v + (v_rest - v + I)/tau_m;
// thresh = theta_s + theta_v; spiked_soft = sigmoid(v' - thresh);
// v_new = (v' >= thresh) ? v_rest : v'.
// Outputs: d_out[0:N] = v_new, d_out[N:2N] = spiked_soft.
// Cost = streaming 268 MB of w once -> HBM-bound, floor ~41-43 us.
//
// Round 5: REVERT to non-temporal w loads (round-3 variant). A/B evidence:
//   r1  no-NT, 256thr        : 374.0 us
//   r3  NT,    512thr        : 352.7 us   <- best
//   r4  no-NT, 512thr, hoist : 374.5 us
// => NT on the once-streamed w is worth ~22 us (avoids L2/L3 thrash of the
// block-shared g copies + victim traffic). Keep 512thr + param hoist.

#define NN 8192
#define THREADS 512
#define ROWS_PER_BLOCK (THREADS / 64)   // 8 rows, one wave each

typedef float floatx4 __attribute__((ext_vector_type(4)));

__global__ __launch_bounds__(THREADS) void glif_kernel(
    const float* __restrict__ x_in,
    const float* __restrict__ w,
    const float* __restrict__ v_in,
    const float* __restrict__ g,
    const float* __restrict__ v_rest,
    const float* __restrict__ tau_m,
    const float* __restrict__ theta_s,
    const float* __restrict__ theta_v,
    float* __restrict__ out_v,
    float* __restrict__ out_spike)
{
    __shared__ float sg[NN];  // 32 KiB: whole g vector staged once per block

    const int tid = threadIdx.x;

    // Cooperative coalesced stage of g into LDS (16 B/lane).
    const floatx4* g4 = reinterpret_cast<const floatx4*>(g);
    floatx4* sg4 = reinterpret_cast<floatx4*>(sg);
    for (int i = tid; i < NN / 4; i += THREADS) {
        sg4[i] = g4[i];
    }

    const int wave = tid >> 6;
    const int lane = tid & 63;
    const int row  = blockIdx.x * ROWS_PER_BLOCK + wave;

    // Lane 0 issues its scalar parameter loads early; results consumed
    // after the dot loop, so their latency hides under the streaming.
    float xi = 0.f, vv = 0.f, vr = 0.f, tm = 1.f, ts = 0.f, tv = 0.f;
    if (lane == 0) {
        xi = x_in[row];
        vv = v_in[row];
        vr = v_rest[row];
        tm = tau_m[row];
        ts = theta_s[row];
        tv = theta_v[row];
    }

    __syncthreads();

    // One wave per row: dot(w[row,:], g). 2048 float4 per row / 64 lanes
    // = 32 x 16B loads/lane, coalesced (1 KiB per wave instruction),
    // independent -> deep memory pipeline. NT: w is streamed exactly once;
    // keeping it out of L2/L3 protects the shared g copies (-22 us, r3 vs r4).
    const floatx4* wrow4 = reinterpret_cast<const floatx4*>(w + (size_t)row * NN);
    float ax = 0.f, ay = 0.f, az = 0.f, aw = 0.f;
    #pragma unroll 8
    for (int j = lane; j < NN / 4; j += 64) {
        floatx4 a = __builtin_nontemporal_load(&wrow4[j]);
        floatx4 b = sg4[j];
        ax = __builtin_fmaf(a.x, b.x, ax);
        ay = __builtin_fmaf(a.y, b.y, ay);
        az = __builtin_fmaf(a.z, b.z, az);
        aw = __builtin_fmaf(a.w, b.w, aw);
    }
    float acc = (ax + ay) + (az + aw);

    // 64-lane butterfly reduce.
    #pragma unroll
    for (int off = 32; off > 0; off >>= 1)
        acc += __shfl_down(acc, off, 64);

    if (lane == 0) {
        // Elementwise GLIF tail for this row (scalar, negligible cost).
        float I  = 1.0f / (1.0f + expf(-(acc + xi)));
        float v  = vv + (vr - vv + I) / tm;
        float thresh = ts + tv;
        float ss = 1.0f / (1.0f + expf(-(v - thresh)));
        float vn = (v >= thresh) ? vr : v;
        out_v[row]     = vn;
        out_spike[row] = ss;
    }
}

extern "C" void kernel_launch(void* const* d_in, const int* in_sizes, int n_in,
                              void* d_out, int out_size, void* d_ws, size_t ws_size,
                              hipStream_t stream) {
    // setup_inputs() order:
    // 0:x_in 1:w 2:v 3:g 4:v_rest 5:tau_m 6:tau_g 7:theta_s 8:theta_v 9:b_s 10:a_v 11:b_v
    const float* x_in    = (const float*)d_in[0];
    const float* w       = (const float*)d_in[1];
    const float* v       = (const float*)d_in[2];
    const float* g       = (const float*)d_in[3];
    const float* v_rest  = (const float*)d_in[4];
    const float* tau_m   = (const float*)d_in[5];
    const float* theta_s = (const float*)d_in[7];
    const float* theta_v = (const float*)d_in[8];

    float* out_v     = (float*)d_out;        // [N] v_new
    float* out_spike = (float*)d_out + NN;   // [N] spiked_soft

    const int blocks = NN / ROWS_PER_BLOCK;  // 1024
    glif_kernel<<<blocks, THREADS, 0, stream>>>(
        x_in, w, v, g, v_rest, tau_m, theta_s, theta_v, out_v, out_spike);
}